// Round 12
// baseline (26.682 us; speedup 1.0000x reference)
//
#include <hip/hip_runtime.h>

// CTC batch cost, B=256 T=512 C=256 L=64 (S=129).
// R12 = R11 (producer/consumer wave split: wid0=fwd DP, wid1=bwd DP,
// wid2..5 = 4 producer waves, 2 per direction; counted-vmcnt producers;
// raw s_barrier rendezvous) with 16-ROW GROUPS: 16 barriers instead of 32.
// R11 lesson: depth, consumer latency-hiding, and producer parallelism are
// all flat -> residual is per-rendezvous overhead (6-wave barrier + restart),
// so halve the rendezvous count. Ring = 64 slots/dir (4 groups, 128 KB LDS),
// producers stage 2 groups ahead (vmcnt(16) steady; group-g loads are its
// producer's positions 8g+1..8g+8, retired>=8g+8 at vmcnt(16)).
// WAR: iter-g writes hit slot-group (g-2)&3, read-complete before barrier
// g-1 < issue point. DP math: f64 linear domain, DPP wave shifts,
// log2-domain cut combine (absmax 0.0 in R6-R11).

constexpr int Bc = 256;
constexpr int Tc = 512;
constexpr int Cc = 256;
constexpr int Lc = 64;
constexpr int NS = 64;          // ring slots per direction = 4 groups x 16 rows

#define EPSF (1e-7f)
#define NEGF (-1e30f)

__device__ __forceinline__ float flog2(float x) {
    float r; asm("v_log_f32 %0, %1" : "=v"(r) : "v"(x)); return r;
}
__device__ __forceinline__ float fexp2(float x) {
    float r; asm("v_exp_f32 %0, %1" : "=v"(r) : "v"(x)); return r;
}
__device__ __forceinline__ float lse2(float a, float b) {
    float m = fmaxf(a, b);
    float d = fminf(a, b) - m;
    return m + flog2(1.f + fexp2(d));
}
// log2 of a positive double via exponent extraction + f32 mantissa log.
__device__ __forceinline__ float dlog2(double x) {
    if (!(x > 1e-300)) return NEGF;
    const int hb = __double2hiint(x);
    const int lb = __double2loint(x);
    const int e  = ((hb >> 20) & 0x7FF) - 1022;
    const double m = __hiloint2double((hb & 0x800FFFFF) | (1022 << 20), lb);
    return flog2((float)m) + (float)e;            // m in [0.5, 1)
}
// double wave shifts via paired 32-bit DPP; 'old' fills the boundary lane.
__device__ __forceinline__ double dpp_up1_d(double old, double src) {   // lane i <- i-1
    const int rl = __builtin_amdgcn_update_dpp(
        __double2loint(old), __double2loint(src), 0x138, 0xF, 0xF, false);
    const int rh = __builtin_amdgcn_update_dpp(
        __double2hiint(old), __double2hiint(src), 0x138, 0xF, 0xF, false);
    return __hiloint2double(rh, rl);
}
__device__ __forceinline__ double dpp_dn1_d(double old, double src) {   // lane i <- i+1
    const int rl = __builtin_amdgcn_update_dpp(
        __double2loint(old), __double2loint(src), 0x130, 0xF, 0xF, false);
    const int rh = __builtin_amdgcn_update_dpp(
        __double2hiint(old), __double2hiint(src), 0x130, 0xF, 0xF, false);
    return __hiloint2double(rh, rl);
}
// async global->LDS: lane l writes bytes [16l,16l+16) of the 1 KB slot.
__device__ __forceinline__ void stage16(const float* g, float* l) {
    __builtin_amdgcn_global_load_lds(
        (const __attribute__((address_space(1))) void*)g,
        (__attribute__((address_space(3))) void*)l, 16, 0, 0);
}

__global__ __launch_bounds__(384, 1) void ctc_fb_kernel(
        const int* __restrict__ y_true,
        const float* __restrict__ y_pred,
        float* __restrict__ out)
{
    const int b    = blockIdx.x;
    const int lane = threadIdx.x & 63;
    const int wid  = threadIdx.x >> 6;

    __shared__ float ring[2][NS][Cc];       // 128 KB
    __shared__ float Cl[64], Ch[64];
    __shared__ float CexS;

    const float* __restrict__ bbase = y_pred + (size_t)b * Tc * Cc;

    double lo = 0.0, hi = 0.0, ex = 0.0;

    if (wid >= 2) {
        // ------------- producer waves: wid-2 = {fwd0, bwd0, fwd1, bwd1} ----
        const int pid  = wid - 2;
        const int dir  = pid & 1;
        const int half = pid >> 1;           // 8-row half of each 16-row group
        // local row u -> global row: fwd u, bwd 511-u.
        const float* __restrict__ g0 =
            dir ? (bbase + (size_t)(Tc - 1) * Cc + lane * 4)
                : (bbase + lane * 4);
        const ptrdiff_t stp = dir ? -(ptrdiff_t)Cc : (ptrdiff_t)Cc;
        float* const lds0 = &ring[dir][0][0];
        // prologue: this half's 8 rows of groups 0..1 (16 loads)
        #pragma unroll
        for (int G = 0; G < 2; ++G) {
            #pragma unroll
            for (int j = 0; j < 8; ++j) {
                const int u = 16 * G + 8 * half + j;
                stage16(g0 + stp * u, lds0 + u * Cc);
            }
        }
        for (int g = 0; g < 16; ++g) {
            if (g <= 13) {                   // stage this half of group g+2
                const int u0 = 16 * (g + 2) + 8 * half;
                const float* gb = g0 + stp * u0;
                float* lb = lds0 + (u0 & 63) * Cc;
                #pragma unroll
                for (int j = 0; j < 8; ++j)
                    stage16(gb + stp * j, lb + j * Cc);
            }
            // group g retired when vmcnt <= (issued - (8g+8))
            if (g <= 13)      asm volatile("s_waitcnt vmcnt(16)" ::: "memory");
            else if (g == 14) asm volatile("s_waitcnt vmcnt(8)"  ::: "memory");
            else              asm volatile("s_waitcnt vmcnt(0)"  ::: "memory");
            __builtin_amdgcn_s_barrier();    // rendezvous #g (raw: no drain)
        }
    } else {
        // ---------------- consumer (DP) waves ----------------
        const int lab  = y_true[b * Lc + lane];
        const int labp = __shfl_up(lab, 1);
        const int labn = __shfl_down(lab, 1);

        float cB0, cB1, cB2, cB3, cB4, cB5, cB6, cB7;
        float cL0, cL1, cL2, cL3, cL4, cL5, cL6, cL7;

        if (wid == 0) {
            // forward DP: steps/rows 0..255
            const bool allowF = (lane >= 1) && (lab != labp);
            auto stepF = [&](float pBf, float pLf) {
                const double pB = (double)pBf, pL = (double)pLf;
                const double prevHi = dpp_up1_d(0.0, hi);
                const double sk  = allowF ? prevHi : 0.0;
                const double nlo = (lo + prevHi) * pB;
                const double nhi = (hi + lo + sk) * pL;
                ex = (ex + hi) * pB;     // real only at lane 63 (127->128)
                hi = nhi; lo = nlo;
            };
            for (int g = 0; g < 16; ++g) {
                const int sb = (g & 3) * 16;
                asm volatile("" ::: "memory");
                __builtin_amdgcn_s_barrier();        // group g ready
                asm volatile("" ::: "memory");
#define RD8F(base)                                                         \
    cL0 = ring[0][(base) + 0][lab] + EPSF; cB0 = ring[0][(base) + 0][Cc-1] + EPSF; \
    cL1 = ring[0][(base) + 1][lab] + EPSF; cB1 = ring[0][(base) + 1][Cc-1] + EPSF; \
    cL2 = ring[0][(base) + 2][lab] + EPSF; cB2 = ring[0][(base) + 2][Cc-1] + EPSF; \
    cL3 = ring[0][(base) + 3][lab] + EPSF; cB3 = ring[0][(base) + 3][Cc-1] + EPSF; \
    cL4 = ring[0][(base) + 4][lab] + EPSF; cB4 = ring[0][(base) + 4][Cc-1] + EPSF; \
    cL5 = ring[0][(base) + 5][lab] + EPSF; cB5 = ring[0][(base) + 5][Cc-1] + EPSF; \
    cL6 = ring[0][(base) + 6][lab] + EPSF; cB6 = ring[0][(base) + 6][Cc-1] + EPSF; \
    cL7 = ring[0][(base) + 7][lab] + EPSF; cB7 = ring[0][(base) + 7][Cc-1] + EPSF;
                RD8F(sb)
                if (g == 0) {
                    lo = (lane == 0) ? (double)cB0 : 0.0;    // alpha0(0)
                    hi = (lane == 0) ? (double)cL0 : 0.0;    // alpha0(1)
                } else stepF(cB0, cL0);
                stepF(cB1, cL1); stepF(cB2, cL2); stepF(cB3, cL3);
                stepF(cB4, cL4); stepF(cB5, cL5); stepF(cB6, cL6);
                stepF(cB7, cL7);
                RD8F(sb + 8)
                stepF(cB0, cL0); stepF(cB1, cL1); stepF(cB2, cL2);
                stepF(cB3, cL3); stepF(cB4, cL4); stepF(cB5, cL5);
                stepF(cB6, cL6); stepF(cB7, cL7);
#undef RD8F
            }
        } else {
            // backward DP: local rows 0..255 <-> t = 511..256
            const bool allowB = (lane < 63) && (labn != lab);
            auto stepB = [&](float pBf, float pLf) {
                const double pB = (double)pBf, pL = (double)pLf;
                const double nlo_s = dpp_dn1_d(ex, lo);   // B(2l+2); l63 <- ex
                const double nhi_s = dpp_dn1_d(0.0, hi);  // B(2l+3); l63 <- 0
                const double sk = allowB ? nhi_s : 0.0;
                const double l2 = (lo + hi) * pB;
                const double h2 = (hi + nlo_s + sk) * pL;
                ex = ex * pB;
                lo = l2; hi = h2;
            };
            for (int g = 0; g < 16; ++g) {
                const int sb = (g & 3) * 16;
                asm volatile("" ::: "memory");
                __builtin_amdgcn_s_barrier();        // group g ready
                asm volatile("" ::: "memory");
#define RD8B(base)                                                         \
    cL0 = ring[1][(base) + 0][lab] + EPSF; cB0 = ring[1][(base) + 0][Cc-1] + EPSF; \
    cL1 = ring[1][(base) + 1][lab] + EPSF; cB1 = ring[1][(base) + 1][Cc-1] + EPSF; \
    cL2 = ring[1][(base) + 2][lab] + EPSF; cB2 = ring[1][(base) + 2][Cc-1] + EPSF; \
    cL3 = ring[1][(base) + 3][lab] + EPSF; cB3 = ring[1][(base) + 3][Cc-1] + EPSF; \
    cL4 = ring[1][(base) + 4][lab] + EPSF; cB4 = ring[1][(base) + 4][Cc-1] + EPSF; \
    cL5 = ring[1][(base) + 5][lab] + EPSF; cB5 = ring[1][(base) + 5][Cc-1] + EPSF; \
    cL6 = ring[1][(base) + 6][lab] + EPSF; cB6 = ring[1][(base) + 6][Cc-1] + EPSF; \
    cL7 = ring[1][(base) + 7][lab] + EPSF; cB7 = ring[1][(base) + 7][Cc-1] + EPSF;
                RD8B(sb)
                if (g == 0) {
                    ex = (double)cB0;                          // beta511(128)
                    hi = (lane == 63) ? (double)cL0 : 0.0;     // beta511(127)
                    lo = 0.0;
                } else stepB(cB0, cL0);
                stepB(cB1, cL1); stepB(cB2, cL2); stepB(cB3, cL3);
                stepB(cB4, cL4); stepB(cB5, cL5); stepB(cB6, cL6);
                stepB(cB7, cL7);
                RD8B(sb + 8)
                stepB(cB0, cL0); stepB(cB1, cL1); stepB(cB2, cL2);
                stepB(cB3, cL3); stepB(cB4, cL4); stepB(cB5, cL5);
                stepB(cB6, cL6); stepB(cB7, cL7);
#undef RD8B
            }
            // cut combine half-step: C(s) = B(s) + B(s+1) + allowB(s)*B(s+2),
            // stored log2-domain (R4 lesson: anti-aligned maxima).
            const double nlo_s = dpp_dn1_d(ex, lo);
            const double nhi_s = dpp_dn1_d(0.0, hi);
            const double sk = allowB ? nhi_s : 0.0;
            Cl[lane] = dlog2(lo + hi);
            Ch[lane] = dlog2(hi + nlo_s + sk);
            if (lane == 63) CexS = dlog2(ex);
        }
    }

    __syncthreads();

    if (wid == 0) {
        const float w1 = dlog2(lo) + Cl[lane];
        const float w2 = dlog2(hi) + Ch[lane];
        float w = lse2(w1, w2);
        if (lane == 63) w = lse2(w, dlog2(ex) + CexS);
        #pragma unroll
        for (int off = 32; off; off >>= 1) w = lse2(w, __shfl_xor(w, off));
        if (lane == 0)
            out[b] = -0.69314718055994530942f * w;     // ln2 * log2 -> ln
    }
}

extern "C" void kernel_launch(void* const* d_in, const int* in_sizes, int n_in,
                              void* d_out, int out_size, void* d_ws, size_t ws_size,
                              hipStream_t stream) {
    const int*   y_true = (const int*)d_in[0];
    const float* y_pred = (const float*)d_in[1];
    float*       out    = (float*)d_out;
    ctc_fb_kernel<<<dim3(Bc), dim3(384), 0, stream>>>(y_true, y_pred, out);
}

// Round 13
// 25.295 us; speedup vs baseline: 1.0548x; 1.0548x over previous
//
#include <hip/hip_runtime.h>

// CTC batch cost, B=256 T=512 C=256 L=64 (S=129).
// R13 = R11 skeleton (wid0=fwd DP, wid1=bwd DP, wid2..5 = 4 producers,
// 8-row groups, 32 raw s_barrier rendezvous, NS=48 ring) but producers use
// REGULAR loads (global_load_dwordx4 -> VGPR -> ds_write_b128, T14 split)
// instead of global_load_lds. R12 lesson: depth, consumer latency-hide,
// producer wave count, and barrier count are ALL flat at ~26.5us /
// 4.85 TB/s -> the only unvaried shared resource is the LDS-DMA path; this
// round A/Bs it against the regular VMEM return path.
// Producer pipeline: after barrier #g issue group g+2 (4 float4 loads, reg
// set parity (g)&1), vmcnt(4) retires group g+1, ds_write it, lgkmcnt(0).
// DP math: f64 linear domain, DPP wave shifts, log2-domain cut combine
// (absmax 0.0 in R6-R12).

constexpr int Bc = 256;
constexpr int Tc = 512;
constexpr int Cc = 256;
constexpr int Lc = 64;
constexpr int NS = 48;          // ring slots per direction = 6 groups x 8 rows

#define EPSF (1e-7f)
#define NEGF (-1e30f)

__device__ __forceinline__ float flog2(float x) {
    float r; asm("v_log_f32 %0, %1" : "=v"(r) : "v"(x)); return r;
}
__device__ __forceinline__ float fexp2(float x) {
    float r; asm("v_exp_f32 %0, %1" : "=v"(r) : "v"(x)); return r;
}
__device__ __forceinline__ float lse2(float a, float b) {
    float m = fmaxf(a, b);
    float d = fminf(a, b) - m;
    return m + flog2(1.f + fexp2(d));
}
// log2 of a positive double via exponent extraction + f32 mantissa log.
__device__ __forceinline__ float dlog2(double x) {
    if (!(x > 1e-300)) return NEGF;
    const int hb = __double2hiint(x);
    const int lb = __double2loint(x);
    const int e  = ((hb >> 20) & 0x7FF) - 1022;
    const double m = __hiloint2double((hb & 0x800FFFFF) | (1022 << 20), lb);
    return flog2((float)m) + (float)e;            // m in [0.5, 1)
}
// double wave shifts via paired 32-bit DPP; 'old' fills the boundary lane.
__device__ __forceinline__ double dpp_up1_d(double old, double src) {   // lane i <- i-1
    const int rl = __builtin_amdgcn_update_dpp(
        __double2loint(old), __double2loint(src), 0x138, 0xF, 0xF, false);
    const int rh = __builtin_amdgcn_update_dpp(
        __double2hiint(old), __double2hiint(src), 0x138, 0xF, 0xF, false);
    return __hiloint2double(rh, rl);
}
__device__ __forceinline__ double dpp_dn1_d(double old, double src) {   // lane i <- i+1
    const int rl = __builtin_amdgcn_update_dpp(
        __double2loint(old), __double2loint(src), 0x130, 0xF, 0xF, false);
    const int rh = __builtin_amdgcn_update_dpp(
        __double2hiint(old), __double2hiint(src), 0x130, 0xF, 0xF, false);
    return __hiloint2double(rh, rl);
}

__global__ __launch_bounds__(384, 1) void ctc_fb_kernel(
        const int* __restrict__ y_true,
        const float* __restrict__ y_pred,
        float* __restrict__ out)
{
    const int b    = blockIdx.x;
    const int lane = threadIdx.x & 63;
    const int wid  = threadIdx.x >> 6;

    __shared__ float ring[2][NS][Cc];       // 96 KB
    __shared__ float Cl[64], Ch[64];
    __shared__ float CexS;

    const float* __restrict__ bbase = y_pred + (size_t)b * Tc * Cc;

    double lo = 0.0, hi = 0.0, ex = 0.0;

    if (wid >= 2) {
        // ------------- producer waves: wid-2 = {fwd0, bwd0, fwd1, bwd1} ----
        const int pid  = wid - 2;
        const int dir  = pid & 1;
        const int half = pid >> 1;           // which 4-row half of each group
        // local row u -> global row: fwd u, bwd 511-u; lane covers 16 B.
        const float* __restrict__ g0 =
            dir ? (bbase + (size_t)(Tc - 1) * Cc + lane * 4)
                : (bbase + lane * 4);
        const ptrdiff_t stp = dir ? -(ptrdiff_t)Cc : (ptrdiff_t)Cc;

        float4 a0, a1, a2, a3, b0, b1, b2, b3;   // two named reg sets (rule #20)

#define GADDR(G, j) (g0 + stp * (8 * (G) + 4 * half + (j)))
#define LADDR(G, j) (&ring[dir][((G) % 6) * 8 + 4 * half + (j)][lane * 4])
#define PLOAD(v0, v1, v2, v3, G)                                   \
        v0 = *(const float4*)GADDR(G, 0);                          \
        v1 = *(const float4*)GADDR(G, 1);                          \
        v2 = *(const float4*)GADDR(G, 2);                          \
        v3 = *(const float4*)GADDR(G, 3);
#define PWRITE(v0, v1, v2, v3, G)                                  \
        *(float4*)LADDR(G, 0) = v0;                                \
        *(float4*)LADDR(G, 1) = v1;                                \
        *(float4*)LADDR(G, 2) = v2;                                \
        *(float4*)LADDR(G, 3) = v3;

        // prologue: load groups 0 (->A) and 1 (->B); write group 0.
        PLOAD(a0, a1, a2, a3, 0)
        PLOAD(b0, b1, b2, b3, 1)
        asm volatile("s_waitcnt vmcnt(4)" ::: "memory");   // group 0 regs ready
        PWRITE(a0, a1, a2, a3, 0)
        asm volatile("s_waitcnt lgkmcnt(0)" ::: "memory");

        for (int g = 0; g < 32; g += 2) {
            // ---- even iter g: issue g+2 -> A; retire+write g+1 from B ----
            asm volatile("" ::: "memory");
            __builtin_amdgcn_s_barrier();                  // #g (raw, no drain)
            asm volatile("" ::: "memory");
            if (g + 2 <= 31) { PLOAD(a0, a1, a2, a3, g + 2) }
            if (g <= 29) asm volatile("s_waitcnt vmcnt(4)" ::: "memory");
            else         asm volatile("s_waitcnt vmcnt(0)" ::: "memory");
            PWRITE(b0, b1, b2, b3, g + 1)
            asm volatile("s_waitcnt lgkmcnt(0)" ::: "memory");
            // ---- odd iter g+1: issue g+3 -> B; retire+write g+2 from A ----
            asm volatile("" ::: "memory");
            __builtin_amdgcn_s_barrier();                  // #g+1
            asm volatile("" ::: "memory");
            if (g + 3 <= 31) { PLOAD(b0, b1, b2, b3, g + 3) }
            if (g + 1 <= 29) asm volatile("s_waitcnt vmcnt(4)" ::: "memory");
            else             asm volatile("s_waitcnt vmcnt(0)" ::: "memory");
            if (g + 2 <= 31) {
                PWRITE(a0, a1, a2, a3, g + 2)
                asm volatile("s_waitcnt lgkmcnt(0)" ::: "memory");
            }
        }
#undef GADDR
#undef LADDR
#undef PLOAD
#undef PWRITE
    } else {
        // ---------------- consumer (DP) waves (R11/R9 form) ----------------
        const int lab  = y_true[b * Lc + lane];
        const int labp = __shfl_up(lab, 1);
        const int labn = __shfl_down(lab, 1);

        if (wid == 0) {
            // forward DP: steps/rows 0..255
            const bool allowF = (lane >= 1) && (lab != labp);
            auto stepF = [&](float pBf, float pLf) {
                const double pB = (double)pBf, pL = (double)pLf;
                const double prevHi = dpp_up1_d(0.0, hi);
                const double sk  = allowF ? prevHi : 0.0;
                const double nlo = (lo + prevHi) * pB;
                const double nhi = (hi + lo + sk) * pL;
                ex = (ex + hi) * pB;     // real only at lane 63 (127->128)
                hi = nhi; lo = nlo;
            };
            int sb = 0;
            for (int g = 0; g < 32; ++g) {
                asm volatile("" ::: "memory");
                __builtin_amdgcn_s_barrier();        // group g ready
                asm volatile("" ::: "memory");
#define RDF(j) const float cL##j = ring[0][sb + j][lab] + EPSF, \
                           cB##j = ring[0][sb + j][Cc - 1] + EPSF;
                RDF(0) RDF(1) RDF(2) RDF(3) RDF(4) RDF(5) RDF(6) RDF(7)
#undef RDF
                if (g == 0) {
                    lo = (lane == 0) ? (double)cB0 : 0.0;    // alpha0(0)
                    hi = (lane == 0) ? (double)cL0 : 0.0;    // alpha0(1)
                } else stepF(cB0, cL0);
                stepF(cB1, cL1); stepF(cB2, cL2); stepF(cB3, cL3);
                stepF(cB4, cL4); stepF(cB5, cL5); stepF(cB6, cL6);
                stepF(cB7, cL7);
                sb += 8; if (sb >= NS) sb = 0;
            }
        } else {
            // backward DP: local rows 0..255 <-> t = 511..256
            const bool allowB = (lane < 63) && (labn != lab);
            auto stepB = [&](float pBf, float pLf) {
                const double pB = (double)pBf, pL = (double)pLf;
                const double nlo_s = dpp_dn1_d(ex, lo);   // B(2l+2); l63 <- ex
                const double nhi_s = dpp_dn1_d(0.0, hi);  // B(2l+3); l63 <- 0
                const double sk = allowB ? nhi_s : 0.0;
                const double l2 = (lo + hi) * pB;
                const double h2 = (hi + nlo_s + sk) * pL;
                ex = ex * pB;
                lo = l2; hi = h2;
            };
            int sb = 0;
            for (int g = 0; g < 32; ++g) {
                asm volatile("" ::: "memory");
                __builtin_amdgcn_s_barrier();        // group g ready
                asm volatile("" ::: "memory");
#define RDB(j) const float cL##j = ring[1][sb + j][lab] + EPSF, \
                           cB##j = ring[1][sb + j][Cc - 1] + EPSF;
                RDB(0) RDB(1) RDB(2) RDB(3) RDB(4) RDB(5) RDB(6) RDB(7)
#undef RDB
                if (g == 0) {
                    ex = (double)cB0;                          // beta511(128)
                    hi = (lane == 63) ? (double)cL0 : 0.0;     // beta511(127)
                    lo = 0.0;
                } else stepB(cB0, cL0);
                stepB(cB1, cL1); stepB(cB2, cL2); stepB(cB3, cL3);
                stepB(cB4, cL4); stepB(cB5, cL5); stepB(cB6, cL6);
                stepB(cB7, cL7);
                sb += 8; if (sb >= NS) sb = 0;
            }
            // cut combine half-step: C(s) = B(s) + B(s+1) + allowB(s)*B(s+2),
            // stored log2-domain (R4 lesson: anti-aligned maxima).
            const double nlo_s = dpp_dn1_d(ex, lo);
            const double nhi_s = dpp_dn1_d(0.0, hi);
            const double sk = allowB ? nhi_s : 0.0;
            Cl[lane] = dlog2(lo + hi);
            Ch[lane] = dlog2(hi + nlo_s + sk);
            if (lane == 63) CexS = dlog2(ex);
        }
    }

    __syncthreads();

    if (wid == 0) {
        const float w1 = dlog2(lo) + Cl[lane];
        const float w2 = dlog2(hi) + Ch[lane];
        float w = lse2(w1, w2);
        if (lane == 63) w = lse2(w, dlog2(ex) + CexS);
        #pragma unroll
        for (int off = 32; off; off >>= 1) w = lse2(w, __shfl_xor(w, off));
        if (lane == 0)
            out[b] = -0.69314718055994530942f * w;     // ln2 * log2 -> ln
    }
}

extern "C" void kernel_launch(void* const* d_in, const int* in_sizes, int n_in,
                              void* d_out, int out_size, void* d_ws, size_t ws_size,
                              hipStream_t stream) {
    const int*   y_true = (const int*)d_in[0];
    const float* y_pred = (const float*)d_in[1];
    float*       out    = (float*)d_out;
    ctc_fb_kernel<<<dim3(Bc), dim3(384), 0, stream>>>(y_true, y_pred, out);
}